// Round 10
// baseline (1930.903 us; speedup 1.0000x reference)
//
#include <hip/hip_runtime.h>
#include <math.h>

#define T_DIM 4096
#define D_DIM 256
#define K_DIM 1024

#define DIFF_OFF 16777216
#define IND_OFF  16777217
#define PERP_OFF 16842753

// ---------------- K1: transpose emb [D,K] -> embT [K,D], compute E_k = sum_d emb[d][k]^2
__global__ void k_transpose(const float* __restrict__ emb, float* __restrict__ embT,
                            float* __restrict__ E) {
    int k = blockIdx.x * 256 + threadIdx.x;   // 1024 codes total
    float e = 0.f;
    for (int d = 0; d < D_DIM; ++d) {
        float v = emb[d * K_DIM + k];         // coalesced across k
        embT[k * D_DIM + d] = v;
        e = fmaf(v, v, e);
    }
    E[k] = e;
}

// ---------------- K2: per-row argmin over K codes
// v3: 32 rows/block (2048 blocks) -> LDS ~35KB -> 4 blocks/CU = 4 waves/SIMD (TLP),
// and 4x4 register tile with cvA/cvB double-buffer that FITS in the 128-VGPR cap
// (round-8 evidence: J=8 needed ~160 VGPR, compiler dropped the pipeline at 128).
__launch_bounds__(256, 4)
__global__ void k_argmin(const float* __restrict__ x, const float* __restrict__ embT,
                         const float* __restrict__ E, float* __restrict__ indf,
                         unsigned* __restrict__ counts) {
    __shared__ float  xs[32][260];     // 32 rows x 256 D, pad 260 -> conflict-free b128 reads
    __shared__ double sred[128];
    __shared__ float  sS[32];

    const int tid = threadIdx.x;
    const int n0  = blockIdx.x * 32;          // 32 rows per block, all within one b
    const int b   = n0 >> 12;                 // T=4096
    const int t0  = n0 & 4095;
    const float* xb = x + (size_t)b * (D_DIM * (size_t)T_DIM) + t0;

    // stage x tile transposed: xs[t][d]; lanes 0..31 share d, consecutive t -> coalesced
    for (int m = 0; m < 32; ++m) {
        int idx = tid + 256 * m;              // 32*256 = 8192 elems
        int d = idx >> 5, tt = idx & 31;
        xs[tt][d] = xb[(size_t)d * T_DIM + tt];
    }
    __syncthreads();

    // S_row = sum_d x^2, EXACT same partition as validated v2: 4 segs of 64 d,
    // f64 partials, one round to f32. threads 0..127 active.
    if (tid < 128) {
        int row = tid >> 2, seg = tid & 3;
        double s = 0.0;
        for (int q = 0; q < 16; ++q) {
            float4 v = *(const float4*)&xs[row][seg * 64 + 4 * q];
            s += (double)v.x * v.x + (double)v.y * v.y + (double)v.z * v.z + (double)v.w * v.w;
        }
        sred[tid] = s;
    }
    __syncthreads();
    if (tid < 32)
        sS[tid] = (float)(sred[4 * tid] + sred[4 * tid + 1] + sred[4 * tid + 2] + sred[4 * tid + 3]);
    __syncthreads();

    const int tc = tid & 31;   // 32 code groups x 4 codes = 128 codes per chunk
    const int tr = tid >> 5;   // 8 row groups x 4 rows = 32 rows

    float bmin[4], Sr[4];
    int   bidx[4];
#pragma unroll
    for (int i = 0; i < 4; ++i) { bmin[i] = INFINITY; bidx[i] = 0; Sr[i] = sS[tr * 4 + i]; }

    for (int chunk = 0; chunk < 8; ++chunk) {
        const int kbase = chunk * 128 + tc * 4;
        const float4* c4 = (const float4*)(embT + (size_t)kbase * D_DIM);

        float acc[4][4];
#pragma unroll
        for (int i = 0; i < 4; ++i)
#pragma unroll
            for (int j = 0; j < 4; ++j) acc[i][j] = 0.f;

        float4 cvA[4], cvB[4];
#pragma unroll
        for (int j = 0; j < 4; ++j) cvA[j] = c4[j * 64];   // preload dq=0

#pragma unroll 1
        for (int dq2 = 0; dq2 < 32; ++dq2) {
            const int dq = 2 * dq2;
            // even step: prefetch dq+1 into cvB, compute with cvA (dq)
#pragma unroll
            for (int j = 0; j < 4; ++j) cvB[j] = c4[j * 64 + dq + 1];
            {
                float4 xv[4];
#pragma unroll
                for (int i = 0; i < 4; ++i) xv[i] = *(const float4*)&xs[tr * 4 + i][4 * dq];
#pragma unroll
                for (int i = 0; i < 4; ++i)
#pragma unroll
                    for (int j = 0; j < 4; ++j) {
                        acc[i][j] = fmaf(xv[i].x, cvA[j].x, acc[i][j]);
                        acc[i][j] = fmaf(xv[i].y, cvA[j].y, acc[i][j]);
                        acc[i][j] = fmaf(xv[i].z, cvA[j].z, acc[i][j]);
                        acc[i][j] = fmaf(xv[i].w, cvA[j].w, acc[i][j]);
                    }
            }
            // odd step: prefetch dq+2 into cvA, compute with cvB (dq+1).
            // Final-iteration prefetch reads 16B past the row span: max address is
            // exactly embT+1MB = E[0..3] in d_ws (mapped, value dead).
#pragma unroll
            for (int j = 0; j < 4; ++j) cvA[j] = c4[j * 64 + dq + 2];
            {
                float4 xv[4];
#pragma unroll
                for (int i = 0; i < 4; ++i) xv[i] = *(const float4*)&xs[tr * 4 + i][4 * dq + 4];
#pragma unroll
                for (int i = 0; i < 4; ++i)
#pragma unroll
                    for (int j = 0; j < 4; ++j) {
                        acc[i][j] = fmaf(xv[i].x, cvB[j].x, acc[i][j]);
                        acc[i][j] = fmaf(xv[i].y, cvB[j].y, acc[i][j]);
                        acc[i][j] = fmaf(xv[i].z, cvB[j].z, acc[i][j]);
                        acc[i][j] = fmaf(xv[i].w, cvB[j].w, acc[i][j]);
                    }
            }
        }

        // epilogue: dist = fl(fl(S - 2*m) + E), strict-< keeps lowest k (k ascends in j, chunk)
#pragma unroll
        for (int j = 0; j < 4; ++j) {
            float Ek = E[kbase + j];
#pragma unroll
            for (int i = 0; i < 4; ++i) {
                float t = fmaf(-2.f, acc[i][j], Sr[i]);  // exact single-rounding of S - 2m
                float dist = t + Ek;
                if (dist < bmin[i]) { bmin[i] = dist; bidx[i] = kbase + j; }
            }
        }
    }

    // half-wave argmin reduce: the 32 threads sharing tr are 32 consecutive lanes,
    // xor masks 1..16 stay within the half-wave. Exact lowest-index tie-break.
#pragma unroll
    for (int i = 0; i < 4; ++i) {
#pragma unroll
        for (int mk = 1; mk <= 16; mk <<= 1) {
            float vo = __shfl_xor(bmin[i], mk, 64);
            int   io = __shfl_xor(bidx[i], mk, 64);
            if (vo < bmin[i] || (vo == bmin[i] && io < bidx[i])) { bmin[i] = vo; bidx[i] = io; }
        }
    }
    if (tc == 0) {
#pragma unroll
        for (int i = 0; i < 4; ++i) {
            indf[n0 + tr * 4 + i] = (float)bidx[i];
            atomicAdd(&counts[bidx[i]], 1u);
        }
    }
}

// ---------------- K3: gather codes, write quant_out (straight-through rounding kept), SSE
__launch_bounds__(256)
__global__ void k_gather(const float* __restrict__ x, const float* __restrict__ embT,
                         const float* __restrict__ indf, float* __restrict__ qout,
                         float* __restrict__ sse) {
    __shared__ int   kk[64];
    __shared__ float cst[256][66];   // [d][t], pad 66 -> 2-way (free) read pattern
    __shared__ float rs[256];

    const int tid = threadIdx.x;
    const int n0  = blockIdx.x * 64;
    const int b   = n0 >> 12;
    const int t0  = n0 & 4095;

    if (tid < 64) kk[tid] = (int)indf[n0 + tid];
    __syncthreads();

    {   // stage gathered code rows transposed into LDS
        int row = tid >> 2, seg = tid & 3;
        const float* cr = embT + (size_t)kk[row] * D_DIM + seg * 64;
        for (int q = 0; q < 16; ++q) {
            float4 v = *(const float4*)(cr + 4 * q);
            int d = seg * 64 + 4 * q;
            cst[d + 0][row] = v.x; cst[d + 1][row] = v.y;
            cst[d + 2][row] = v.z; cst[d + 3][row] = v.w;
        }
    }
    __syncthreads();

    const int lane = tid & 63, w = tid >> 6;
    const size_t base = (size_t)b * (D_DIM * (size_t)T_DIM) + t0 + lane;
    float local = 0.f;
    for (int m = 0; m < 64; ++m) {
        int d = w * 64 + m;
        float xv = x[base + (size_t)d * T_DIM];   // coalesced along t
        float q  = cst[d][lane];
        float dlt = q - xv;                        // quant - x (used for mse)
        qout[base + (size_t)d * T_DIM] = xv + dlt; // straight-through: x + (q - x), keep roundings
        local = fmaf(dlt, dlt, local);
    }

    rs[tid] = local; __syncthreads();
    for (int s = 128; s > 0; s >>= 1) { if (tid < s) rs[tid] += rs[tid + s]; __syncthreads(); }
    if (tid == 0) atomicAdd(sse, rs[0]);
}

// ---------------- K4: scalars (diff, perplexity)
__global__ void k_final(const unsigned* __restrict__ counts, const float* __restrict__ sse,
                        float* __restrict__ out) {
    __shared__ float rs[256];
    int tid = threadIdx.x;
    float local = 0.f;
    for (int q = 0; q < 4; ++q) {
        unsigned c = counts[tid * 4 + q];
        float p = (float)c * (1.f / 65536.f);
        local += p * logf(p + 1e-10f);
    }
    rs[tid] = local; __syncthreads();
    for (int s = 128; s > 0; s >>= 1) { if (tid < s) rs[tid] += rs[tid + s]; __syncthreads(); }
    if (tid == 0) {
        out[PERP_OFF] = expf(-rs[0]);
        float m = *sse * (1.f / 16777216.f);   // mean over B*T*D = 2^24 (exact scale)
        out[DIFF_OFF] = 0.25f * m + m;         // matches fl(0.25*m) + m
    }
}

extern "C" void kernel_launch(void* const* d_in, const int* in_sizes, int n_in,
                              void* d_out, int out_size, void* d_ws, size_t ws_size,
                              hipStream_t stream) {
    const float* x   = (const float*)d_in[0];
    const float* emb = (const float*)d_in[1];
    float* out = (float*)d_out;

    char* w = (char*)d_ws;
    float*    embT   = (float*)(w);                          // 1 MB (k_argmin may read 16B past: lands in E)
    float*    E      = (float*)(w + (1u << 20));             // 4 KB
    unsigned* counts = (unsigned*)(w + (1u << 20) + 4096);   // 4 KB
    float*    sse    = (float*)(w + (1u << 20) + 8192);      // 4 B

    hipMemsetAsync(w + (1u << 20) + 4096, 0, 8192, stream);  // zero counts + sse

    k_transpose<<<dim3(4), dim3(256), 0, stream>>>(emb, embT, E);
    k_argmin  <<<dim3(2048), dim3(256), 0, stream>>>(x, embT, E, out + IND_OFF, counts);
    k_gather  <<<dim3(1024), dim3(256), 0, stream>>>(x, embT, out + IND_OFF, out, sse);
    k_final   <<<dim3(1), dim3(256), 0, stream>>>(counts, sse, out);
}

// Round 12
// 1053.437 us; speedup vs baseline: 1.8330x; 1.8330x over previous
//
#include <hip/hip_runtime.h>
#include <math.h>

#define T_DIM 4096
#define D_DIM 256
#define K_DIM 1024

#define DIFF_OFF 16777216
#define IND_OFF  16777217
#define PERP_OFF 16842753

// ---------------- K1: transpose emb [D,K] -> embT [K,D], compute E_k = sum_d emb[d][k]^2
__global__ void k_transpose(const float* __restrict__ emb, float* __restrict__ embT,
                            float* __restrict__ E) {
    int k = blockIdx.x * 256 + threadIdx.x;   // 1024 codes total
    float e = 0.f;
    for (int d = 0; d < D_DIM; ++d) {
        float v = emb[d * K_DIM + k];         // coalesced across k
        embT[k * D_DIM + d] = v;
        e = fmaf(v, v, e);
    }
    E[k] = e;
}

// ---------------- K2: per-row argmin over K codes (the GEMM + argmin)
// v5 = round-8 v2 (measured 1017us, VALUBusy 31.6% at VGPR=128 CAP) with the cap
// lifted: __launch_bounds__(256,2) -> 256 VGPR budget. Round-8/10 evidence:
// VGPR 60 -> 19.5% busy; VGPR 128 (at cap) -> 31.6% busy. The J=8 double-buffer
// needs ~160-220 live regs for the full software pipeline; give the allocator room.
__launch_bounds__(256, 2)
__global__ void k_argmin(const float* __restrict__ x, const float* __restrict__ embT,
                         const float* __restrict__ E, float* __restrict__ indf,
                         unsigned* __restrict__ counts) {
    __shared__ float  xs[64][260];     // 64 rows x 256 D, pad 260 -> conflict-free frag reads
    __shared__ double sred[256];
    __shared__ float  sS[64];

    const int tid = threadIdx.x;
    const int n0  = blockIdx.x * 64;          // 64 rows per block, all within one b
    const int b   = n0 >> 12;                 // T=4096
    const int t0  = n0 & 4095;
    const float* xb = x + (size_t)b * (D_DIM * (size_t)T_DIM) + t0;

    // stage x tile transposed: xs[t][d]; coalesced along t
    for (int m = 0; m < 64; ++m) {
        int idx = tid + 256 * m;
        int d = idx >> 6, tt = idx & 63;
        xs[tt][d] = xb[(size_t)d * T_DIM + tt];
    }
    __syncthreads();

    // S_row = sum_d x^2 (f64 accumulate, single round to f32)
    {
        int row = tid >> 2, seg = tid & 3;
        double s = 0.0;
        for (int q = 0; q < 16; ++q) {
            float4 v = *(const float4*)&xs[row][seg * 64 + 4 * q];
            s += (double)v.x * v.x + (double)v.y * v.y + (double)v.z * v.z + (double)v.w * v.w;
        }
        sred[tid] = s;
    }
    __syncthreads();
    if (tid < 64)
        sS[tid] = (float)(sred[4 * tid] + sred[4 * tid + 1] + sred[4 * tid + 2] + sred[4 * tid + 3]);
    __syncthreads();

    const int tc = tid & 31;   // 32 code groups x 8 codes = 256 codes per chunk
    const int tr = tid >> 5;   // 8 row groups x 8 rows = 64 rows

    float bmin[8], Sr[8];
    int   bidx[8];
#pragma unroll
    for (int i = 0; i < 8; ++i) { bmin[i] = INFINITY; bidx[i] = 0; Sr[i] = sS[tr * 8 + i]; }

    for (int chunk = 0; chunk < 4; ++chunk) {
        const int kbase = chunk * 256 + tc * 8;
        const float4* c4 = (const float4*)(embT + (size_t)kbase * D_DIM);

        float acc[8][8];
#pragma unroll
        for (int i = 0; i < 8; ++i)
#pragma unroll
            for (int j = 0; j < 8; ++j) acc[i][j] = 0.f;

        float4 cvA[8], cvB[8];
#pragma unroll
        for (int j = 0; j < 8; ++j) cvA[j] = c4[j * 64];   // preload dq=0

#pragma unroll 1
        for (int dq2 = 0; dq2 < 32; ++dq2) {
            const int dq = 2 * dq2;
            // even step: prefetch dq+1, compute with cvA (dq)
#pragma unroll
            for (int j = 0; j < 8; ++j) cvB[j] = c4[j * 64 + dq + 1];
            {
                float4 xv[8];
#pragma unroll
                for (int i = 0; i < 8; ++i) xv[i] = *(const float4*)&xs[tr * 8 + i][4 * dq];
#pragma unroll
                for (int i = 0; i < 8; ++i)
#pragma unroll
                    for (int j = 0; j < 8; ++j) {
                        acc[i][j] = fmaf(xv[i].x, cvA[j].x, acc[i][j]);
                        acc[i][j] = fmaf(xv[i].y, cvA[j].y, acc[i][j]);
                        acc[i][j] = fmaf(xv[i].z, cvA[j].z, acc[i][j]);
                        acc[i][j] = fmaf(xv[i].w, cvA[j].w, acc[i][j]);
                    }
            }
            // odd step: prefetch dq+2, compute with cvB (dq+1).
            // On the final iteration this prefetch reads 16B past the row span;
            // max address is exactly embT+1MB which is E[0..3] in d_ws (mapped, value dead).
#pragma unroll
            for (int j = 0; j < 8; ++j) cvA[j] = c4[j * 64 + dq + 2];
            {
                float4 xv[8];
#pragma unroll
                for (int i = 0; i < 8; ++i) xv[i] = *(const float4*)&xs[tr * 8 + i][4 * dq + 4];
#pragma unroll
                for (int i = 0; i < 8; ++i)
#pragma unroll
                    for (int j = 0; j < 8; ++j) {
                        acc[i][j] = fmaf(xv[i].x, cvB[j].x, acc[i][j]);
                        acc[i][j] = fmaf(xv[i].y, cvB[j].y, acc[i][j]);
                        acc[i][j] = fmaf(xv[i].z, cvB[j].z, acc[i][j]);
                        acc[i][j] = fmaf(xv[i].w, cvB[j].w, acc[i][j]);
                    }
            }
        }

        // epilogue: dist = fl(fl(S - 2*m) + E), strict-< keeps lowest k (k ascends in j, chunk)
#pragma unroll
        for (int j = 0; j < 8; ++j) {
            float Ek = E[kbase + j];
#pragma unroll
            for (int i = 0; i < 8; ++i) {
                float t = fmaf(-2.f, acc[i][j], Sr[i]);  // exact single-rounding of S - 2m
                float dist = t + Ek;
                if (dist < bmin[i]) { bmin[i] = dist; bidx[i] = kbase + j; }
            }
        }
    }

    // half-wave argmin reduce: the 32 threads sharing tr are 32 consecutive lanes,
    // xor masks 1..16 stay within the half-wave. Exact lowest-index tie-break.
#pragma unroll
    for (int i = 0; i < 8; ++i) {
#pragma unroll
        for (int mk = 1; mk <= 16; mk <<= 1) {
            float vo = __shfl_xor(bmin[i], mk, 64);
            int   io = __shfl_xor(bidx[i], mk, 64);
            if (vo < bmin[i] || (vo == bmin[i] && io < bidx[i])) { bmin[i] = vo; bidx[i] = io; }
        }
    }
    if (tc == 0) {
#pragma unroll
        for (int i = 0; i < 8; ++i) {
            indf[n0 + tr * 8 + i] = (float)bidx[i];
            atomicAdd(&counts[bidx[i]], 1u);
        }
    }
}

// ---------------- K3: gather codes, write quant_out (straight-through rounding kept), SSE
__launch_bounds__(256)
__global__ void k_gather(const float* __restrict__ x, const float* __restrict__ embT,
                         const float* __restrict__ indf, float* __restrict__ qout,
                         float* __restrict__ sse) {
    __shared__ int   kk[64];
    __shared__ float cst[256][66];   // [d][t], pad 66 -> 2-way (free) read pattern
    __shared__ float rs[256];

    const int tid = threadIdx.x;
    const int n0  = blockIdx.x * 64;
    const int b   = n0 >> 12;
    const int t0  = n0 & 4095;

    if (tid < 64) kk[tid] = (int)indf[n0 + tid];
    __syncthreads();

    {   // stage gathered code rows transposed into LDS
        int row = tid >> 2, seg = tid & 3;
        const float* cr = embT + (size_t)kk[row] * D_DIM + seg * 64;
        for (int q = 0; q < 16; ++q) {
            float4 v = *(const float4*)(cr + 4 * q);
            int d = seg * 64 + 4 * q;
            cst[d + 0][row] = v.x; cst[d + 1][row] = v.y;
            cst[d + 2][row] = v.z; cst[d + 3][row] = v.w;
        }
    }
    __syncthreads();

    const int lane = tid & 63, w = tid >> 6;
    const size_t base = (size_t)b * (D_DIM * (size_t)T_DIM) + t0 + lane;
    float local = 0.f;
    for (int m = 0; m < 64; ++m) {
        int d = w * 64 + m;
        float xv = x[base + (size_t)d * T_DIM];   // coalesced along t
        float q  = cst[d][lane];
        float dlt = q - xv;                        // quant - x (used for mse)
        qout[base + (size_t)d * T_DIM] = xv + dlt; // straight-through: x + (q - x), keep roundings
        local = fmaf(dlt, dlt, local);
    }

    rs[tid] = local; __syncthreads();
    for (int s = 128; s > 0; s >>= 1) { if (tid < s) rs[tid] += rs[tid + s]; __syncthreads(); }
    if (tid == 0) atomicAdd(sse, rs[0]);
}

// ---------------- K4: scalars (diff, perplexity)
__global__ void k_final(const unsigned* __restrict__ counts, const float* __restrict__ sse,
                        float* __restrict__ out) {
    __shared__ float rs[256];
    int tid = threadIdx.x;
    float local = 0.f;
    for (int q = 0; q < 4; ++q) {
        unsigned c = counts[tid * 4 + q];
        float p = (float)c * (1.f / 65536.f);
        local += p * logf(p + 1e-10f);
    }
    rs[tid] = local; __syncthreads();
    for (int s = 128; s > 0; s >>= 1) { if (tid < s) rs[tid] += rs[tid + s]; __syncthreads(); }
    if (tid == 0) {
        out[PERP_OFF] = expf(-rs[0]);
        float m = *sse * (1.f / 16777216.f);   // mean over B*T*D = 2^24 (exact scale)
        out[DIFF_OFF] = 0.25f * m + m;         // matches fl(0.25*m) + m
    }
}

extern "C" void kernel_launch(void* const* d_in, const int* in_sizes, int n_in,
                              void* d_out, int out_size, void* d_ws, size_t ws_size,
                              hipStream_t stream) {
    const float* x   = (const float*)d_in[0];
    const float* emb = (const float*)d_in[1];
    float* out = (float*)d_out;

    char* w = (char*)d_ws;
    float*    embT   = (float*)(w);                          // 1 MB (k_argmin may read 16B past: lands in E)
    float*    E      = (float*)(w + (1u << 20));             // 4 KB
    unsigned* counts = (unsigned*)(w + (1u << 20) + 4096);   // 4 KB
    float*    sse    = (float*)(w + (1u << 20) + 8192);      // 4 B

    hipMemsetAsync(w + (1u << 20) + 4096, 0, 8192, stream);  // zero counts + sse

    k_transpose<<<dim3(4), dim3(256), 0, stream>>>(emb, embT, E);
    k_argmin  <<<dim3(1024), dim3(256), 0, stream>>>(x, embT, E, out + IND_OFF, counts);
    k_gather  <<<dim3(1024), dim3(256), 0, stream>>>(x, embT, out + IND_OFF, out, sse);
    k_final   <<<dim3(1), dim3(256), 0, stream>>>(counts, sse, out);
}